// Round 3
// baseline (558.237 us; speedup 1.0000x reference)
//
#include <hip/hip_runtime.h>

#define N_NODES 100000
#define N_EDGES 1250000
#define DIM 64
#define EDGE_DIM 10
#define BN_EPS 1e-5f

#define SCAN_CHUNK 1024
#define NB_SCAN ((N_NODES + SCAN_CHUNK - 1) / SCAN_CHUNK)   // 98

// workspace layout (ints)
#define DEG_OFF    0
#define OFFS_OFF   (DEG_OFF + N_NODES)      // start offsets (exclusive prefix)
#define CUR_OFF    (OFFS_OFF + N_NODES)     // cursor; == end offset after scatter
#define BSUM_OFF   (CUR_OFF + N_NODES)      // 128 block sums
#define CSR_OFF    (BSUM_OFF + 128)         // 1.25M edge ids
#define SUMS_OFF_I (CSR_OFF + N_EDGES)      // 256 floats for BN

// -----------------------------------------------------------------------------
// 1) degree histogram
// -----------------------------------------------------------------------------
extern "C" __global__ __launch_bounds__(256)
void degree_kernel(const int* __restrict__ ei, int* __restrict__ deg)
{
    int e = blockIdx.x * 256 + threadIdx.x;
    if (e < N_EDGES) {
        unsigned d = (unsigned)ei[N_EDGES + e];
        d = d < N_NODES ? d : (N_NODES - 1);
        atomicAdd(&deg[d], 1);
    }
}

// -----------------------------------------------------------------------------
// 2a) per-chunk sums (1024 elems / block)
// -----------------------------------------------------------------------------
extern "C" __global__ __launch_bounds__(256)
void scan_bsum_kernel(const int* __restrict__ deg, int* __restrict__ bsum)
{
    __shared__ int sw[4];
    int tid = threadIdx.x;
    int base = blockIdx.x * SCAN_CHUNK + tid * 4;
    int s = 0;
    #pragma unroll
    for (int j = 0; j < 4; ++j) {
        int idx = base + j;
        if (idx < N_NODES) s += deg[idx];
    }
    #pragma unroll
    for (int m = 1; m < 64; m <<= 1) s += __shfl_xor(s, m, 64);
    if ((tid & 63) == 0) sw[tid >> 6] = s;
    __syncthreads();
    if (tid == 0) bsum[blockIdx.x] = sw[0] + sw[1] + sw[2] + sw[3];
}

// -----------------------------------------------------------------------------
// 2b) exclusive scan of the 98 chunk sums (one block, 128 threads)
// -----------------------------------------------------------------------------
extern "C" __global__ __launch_bounds__(128)
void scan_top_kernel(int* __restrict__ bsum)
{
    __shared__ int s[128];
    int tid = threadIdx.x;
    int v = (tid < NB_SCAN) ? bsum[tid] : 0;
    s[tid] = v;
    __syncthreads();
    #pragma unroll
    for (int off = 1; off < 128; off <<= 1) {
        int t = (tid >= off) ? s[tid - off] : 0;
        __syncthreads();
        s[tid] += t;
        __syncthreads();
    }
    if (tid < NB_SCAN) bsum[tid] = s[tid] - v;   // exclusive
}

// -----------------------------------------------------------------------------
// 2c) final offsets: in-chunk scan + chunk base; write offs and cursor
// -----------------------------------------------------------------------------
extern "C" __global__ __launch_bounds__(256)
void scan_final_kernel(const int* __restrict__ deg, const int* __restrict__ bsum,
                       int* __restrict__ offs, int* __restrict__ cur)
{
    __shared__ int s[256];
    int tid = threadIdx.x;
    int base = blockIdx.x * SCAN_CHUNK + tid * 4;
    int d[4];
    #pragma unroll
    for (int j = 0; j < 4; ++j) {
        int idx = base + j;
        d[j] = (idx < N_NODES) ? deg[idx] : 0;
    }
    int tot = d[0] + d[1] + d[2] + d[3];
    s[tid] = tot;
    __syncthreads();
    #pragma unroll
    for (int off = 1; off < 256; off <<= 1) {
        int t = (tid >= off) ? s[tid - off] : 0;
        __syncthreads();
        s[tid] += t;
        __syncthreads();
    }
    int b = bsum[blockIdx.x] + s[tid] - tot;   // exclusive prefix for this thread
    #pragma unroll
    for (int j = 0; j < 4; ++j) {
        int idx = base + j;
        if (idx < N_NODES) { offs[idx] = b; cur[idx] = b; }
        b += d[j];
    }
}

// -----------------------------------------------------------------------------
// 3) scatter edge ids into CSR
// -----------------------------------------------------------------------------
extern "C" __global__ __launch_bounds__(256)
void scatter_kernel(const int* __restrict__ ei, int* __restrict__ cur,
                    int* __restrict__ csr)
{
    int e = blockIdx.x * 256 + threadIdx.x;
    if (e < N_EDGES) {
        unsigned d = (unsigned)ei[N_EDGES + e];
        d = d < N_NODES ? d : (N_NODES - 1);
        int pos = atomicAdd(&cur[d], 1);
        csr[pos] = e;
    }
}

// -----------------------------------------------------------------------------
// 4) fused: CSR gather-aggregate + 2-layer MLP + BN partial sums.
//    64-node tile per block, 8 waves, wave handles 8 nodes, lane = feature.
//    Edge loop unrolled 4-wide: independent gathers pipeline.
// -----------------------------------------------------------------------------
extern "C" __global__ __launch_bounds__(512)
void node_csr_kernel(const float* __restrict__ x,
                     const int* __restrict__ ei,
                     const float* __restrict__ ea,
                     const float* __restrict__ We,
                     const float* __restrict__ be,
                     const int* __restrict__ offs,
                     const int* __restrict__ cur,
                     const int* __restrict__ csr,
                     const float* __restrict__ W1,
                     const float* __restrict__ b1,
                     const float* __restrict__ W2,
                     const float* __restrict__ b2,
                     float* __restrict__ out,
                     float* __restrict__ sums)
{
    __shared__ __align__(16) float sW1[DIM * DIM];
    __shared__ __align__(16) float sW2[DIM * DIM];
    __shared__ __align__(16) float sT[DIM * 68];   // [feat][node], pad 68

    int tid  = threadIdx.x;
    int lane = tid & 63;
    int wv   = tid >> 6;
    int base = blockIdx.x * 64;

    for (int i = tid; i < DIM * DIM; i += 512) {
        sW1[i] = W1[i];
        sW2[i] = W2[i];
    }

    float wcol[EDGE_DIM];
    #pragma unroll
    for (int k = 0; k < EDGE_DIM; ++k) wcol[k] = We[k * DIM + lane];
    float bias = be[lane];

    // ---- phase A: aggregation over contiguous CSR lists ----
    #pragma unroll 1
    for (int t = 0; t < 8; ++t) {
        int nl = wv * 8 + t;
        int v  = base + nl;
        float acc = 0.0f;
        if (v < N_NODES) {
            acc = x[(size_t)v * DIM + lane];
            int stt = __builtin_amdgcn_readfirstlane(offs[v]);
            int end = __builtin_amdgcn_readfirstlane(cur[v]);   // == end offset
            int i = stt;
            for (; i + 4 <= end; i += 4) {
                int e0 = __builtin_amdgcn_readfirstlane(csr[i + 0]);
                int e1 = __builtin_amdgcn_readfirstlane(csr[i + 1]);
                int e2 = __builtin_amdgcn_readfirstlane(csr[i + 2]);
                int e3 = __builtin_amdgcn_readfirstlane(csr[i + 3]);
                int s0 = __builtin_amdgcn_readfirstlane(ei[e0]);
                int s1 = __builtin_amdgcn_readfirstlane(ei[e1]);
                int s2 = __builtin_amdgcn_readfirstlane(ei[e2]);
                int s3 = __builtin_amdgcn_readfirstlane(ei[e3]);
                float x0 = x[(size_t)s0 * DIM + lane];
                float x1 = x[(size_t)s1 * DIM + lane];
                float x2 = x[(size_t)s2 * DIM + lane];
                float x3 = x[(size_t)s3 * DIM + lane];
                float m0 = bias, m1 = bias, m2 = bias, m3 = bias;
                #pragma unroll
                for (int k = 0; k < EDGE_DIM; ++k) {
                    m0 = fmaf(ea[(size_t)e0 * EDGE_DIM + k], wcol[k], m0);
                    m1 = fmaf(ea[(size_t)e1 * EDGE_DIM + k], wcol[k], m1);
                    m2 = fmaf(ea[(size_t)e2 * EDGE_DIM + k], wcol[k], m2);
                    m3 = fmaf(ea[(size_t)e3 * EDGE_DIM + k], wcol[k], m3);
                }
                acc += fmaxf(m0 + x0, 0.0f);
                acc += fmaxf(m1 + x1, 0.0f);
                acc += fmaxf(m2 + x2, 0.0f);
                acc += fmaxf(m3 + x3, 0.0f);
            }
            for (; i < end; ++i) {
                int e0 = __builtin_amdgcn_readfirstlane(csr[i]);
                int s0 = __builtin_amdgcn_readfirstlane(ei[e0]);
                float x0 = x[(size_t)s0 * DIM + lane];
                float m0 = bias;
                #pragma unroll
                for (int k = 0; k < EDGE_DIM; ++k)
                    m0 = fmaf(ea[(size_t)e0 * EDGE_DIM + k], wcol[k], m0);
                acc += fmaxf(m0 + x0, 0.0f);
            }
        }
        sT[lane * 68 + nl] = acc;
    }
    __syncthreads();

    // ---- phase B: two GEMMs, 4 nodes x 2 feats per thread ----
    int i0 = (tid & 15) * 4;   // node offset
    int j0 = (tid >> 4) * 2;   // feature offset

    float acc1[4][2] = {};
    #pragma unroll 8
    for (int k = 0; k < DIM; ++k) {
        float4 av = *(const float4*)&sT[k * 68 + i0];
        float bw0 = sW1[k * DIM + j0];
        float bw1 = sW1[k * DIM + j0 + 1];
        float a4[4] = {av.x, av.y, av.z, av.w};
        #pragma unroll
        for (int a = 0; a < 4; ++a) {
            acc1[a][0] = fmaf(a4[a], bw0, acc1[a][0]);
            acc1[a][1] = fmaf(a4[a], bw1, acc1[a][1]);
        }
    }
    __syncthreads();

    float b1a[2] = {b1[j0], b1[j0 + 1]};
    float tv[4][2];
    #pragma unroll
    for (int a = 0; a < 4; ++a)
        #pragma unroll
        for (int b = 0; b < 2; ++b)
            tv[a][b] = fmaxf(acc1[a][b] + b1a[b], 0.0f);

    #pragma unroll
    for (int b = 0; b < 2; ++b) {
        float4 w = make_float4(tv[0][b], tv[1][b], tv[2][b], tv[3][b]);
        *(float4*)&sT[(j0 + b) * 68 + i0] = w;
    }
    __syncthreads();

    float acc2[4][2] = {};
    #pragma unroll 8
    for (int k = 0; k < DIM; ++k) {
        float4 av = *(const float4*)&sT[k * 68 + i0];
        float bw0 = sW2[k * DIM + j0];
        float bw1 = sW2[k * DIM + j0 + 1];
        float a4[4] = {av.x, av.y, av.z, av.w};
        #pragma unroll
        for (int a = 0; a < 4; ++a) {
            acc2[a][0] = fmaf(a4[a], bw0, acc2[a][0]);
            acc2[a][1] = fmaf(a4[a], bw1, acc2[a][1]);
        }
    }

    float b2a[2] = {b2[j0], b2[j0 + 1]};
    float ps[2] = {0.f, 0.f};
    float pq[2] = {0.f, 0.f};
    #pragma unroll
    for (int a = 0; a < 4; ++a) {
        int n = base + i0 + a;
        float r0 = fmaxf(acc2[a][0] + b2a[0], 0.0f);
        float r1 = fmaxf(acc2[a][1] + b2a[1], 0.0f);
        if (n < N_NODES) {
            float2 w = make_float2(r0, r1);
            *(float2*)&out[(size_t)n * DIM + j0] = w;
            ps[0] += r0; ps[1] += r1;
            pq[0] += r0 * r0; pq[1] += r1 * r1;
        }
    }

    #pragma unroll
    for (int m = 1; m < 16; m <<= 1) {
        #pragma unroll
        for (int b = 0; b < 2; ++b) {
            ps[b] += __shfl_xor(ps[b], m, 64);
            pq[b] += __shfl_xor(pq[b], m, 64);
        }
    }
    if ((lane & 15) == 0) {
        #pragma unroll
        for (int b = 0; b < 2; ++b) {
            unsafeAtomicAdd(&sums[j0 + b], ps[b]);
            unsafeAtomicAdd(&sums[64 + j0 + b], pq[b]);
        }
    }
}

// -----------------------------------------------------------------------------
// BN stats + apply
// -----------------------------------------------------------------------------
extern "C" __global__ void bn_stats_kernel(float* __restrict__ sums,
                                           const float* __restrict__ gamma,
                                           const float* __restrict__ beta)
{
    int f = threadIdx.x;
    float inv_n = 1.0f / (float)N_NODES;
    float mean = sums[f] * inv_n;
    float var  = sums[64 + f] * inv_n - mean * mean;
    float sc   = gamma[f] * rsqrtf(var + BN_EPS);
    sums[128 + f] = sc;
    sums[192 + f] = beta[f] - mean * sc;
}

extern "C" __global__ __launch_bounds__(256)
void bn_apply_kernel(float* __restrict__ out, const float* __restrict__ sums)
{
    int j = blockIdx.x * 256 + threadIdx.x;
    int f0 = (j & 15) * 4;
    float4 sc = *(const float4*)&sums[128 + f0];
    float4 sh = *(const float4*)&sums[192 + f0];
    float4 v = ((float4*)out)[j];
    v.x = fmaf(v.x, sc.x, sh.x);
    v.y = fmaf(v.y, sc.y, sh.y);
    v.z = fmaf(v.z, sc.z, sh.z);
    v.w = fmaf(v.w, sc.w, sh.w);
    ((float4*)out)[j] = v;
}

extern "C" void kernel_launch(void* const* d_in, const int* in_sizes, int n_in,
                              void* d_out, int out_size, void* d_ws, size_t ws_size,
                              hipStream_t stream)
{
    const float* x     = (const float*)d_in[0];
    const int*   ei    = (const int*)  d_in[1];
    const float* ea    = (const float*)d_in[2];
    const float* We    = (const float*)d_in[3];
    const float* be    = (const float*)d_in[4];
    const float* W1    = (const float*)d_in[5];
    const float* b1    = (const float*)d_in[6];
    const float* W2    = (const float*)d_in[7];
    const float* b2    = (const float*)d_in[8];
    const float* gamma = (const float*)d_in[9];
    const float* beta  = (const float*)d_in[10];

    float* out  = (float*)d_out;
    int*   wsi  = (int*)d_ws;
    int*   deg  = wsi + DEG_OFF;
    int*   offs = wsi + OFFS_OFF;
    int*   cur  = wsi + CUR_OFF;
    int*   bsum = wsi + BSUM_OFF;
    int*   csr  = wsi + CSR_OFF;
    float* sums = (float*)(wsi + SUMS_OFF_I);

    hipMemsetAsync(deg, 0, (size_t)N_NODES * sizeof(int), stream);
    hipMemsetAsync(sums, 0, 256 * sizeof(float), stream);

    degree_kernel<<<(N_EDGES + 255) / 256, 256, 0, stream>>>(ei, deg);
    scan_bsum_kernel<<<NB_SCAN, 256, 0, stream>>>(deg, bsum);
    scan_top_kernel<<<1, 128, 0, stream>>>(bsum);
    scan_final_kernel<<<NB_SCAN, 256, 0, stream>>>(deg, bsum, offs, cur);
    scatter_kernel<<<(N_EDGES + 255) / 256, 256, 0, stream>>>(ei, cur, csr);

    node_csr_kernel<<<(N_NODES + 63) / 64, 512, 0, stream>>>(
        x, ei, ea, We, be, offs, cur, csr, W1, b1, W2, b2, out, sums);

    bn_stats_kernel<<<1, 64, 0, stream>>>(sums, gamma, beta);

    bn_apply_kernel<<<(N_NODES * DIM / 4) / 256, 256, 0, stream>>>(out, sums);
}

// Round 4
// 489.271 us; speedup vs baseline: 1.1410x; 1.1410x over previous
//
#include <hip/hip_runtime.h>

#define N_NODES 100000
#define N_EDGES 1250000
#define DIM 64
#define EDGE_DIM 10
#define BN_EPS 1e-5f

#define SCAN_CHUNK 1024
#define NB_SCAN ((N_NODES + SCAN_CHUNK - 1) / SCAN_CHUNK)   // 98

// workspace layout (int units)
#define DEG_OFF    0
#define SUMS_OFF_I (DEG_OFF + N_NODES)        // 256 floats (BN sums/sq/scale/shift)
#define OFFS_OFF   (SUMS_OFF_I + 256)
#define CUR_OFF    (OFFS_OFF + N_NODES)
#define BSUM_OFF   (CUR_OFF + N_NODES)
#define CSR_OFF    (BSUM_OFF + 128)
#define SSRC_OFF   (CSR_OFF + N_EDGES)
#define XH_OFF_I   (SSRC_OFF + N_EDGES)       // 6.4M ushort = 3.2M ints
// total = XH_OFF_I + 3.2M ints ~= 24.0 MB

__device__ __forceinline__ float bf2f(unsigned short h) {
    return __uint_as_float(((unsigned)h) << 16);
}

// -----------------------------------------------------------------------------
// prep: x -> bf16 copy (RTNE) + degree histogram, one grid-stride kernel
// -----------------------------------------------------------------------------
extern "C" __global__ __launch_bounds__(256)
void prep_kernel(const float* __restrict__ x, unsigned short* __restrict__ xh,
                 const int* __restrict__ ei, int* __restrict__ deg)
{
    int t = blockIdx.x * 256 + threadIdx.x;
    int stride = gridDim.x * 256;
    for (int i = t; i < N_NODES * DIM; i += stride) {
        unsigned b = __float_as_uint(x[i]);
        unsigned r = (b + 0x7FFFu + ((b >> 16) & 1u)) >> 16;
        xh[i] = (unsigned short)r;
    }
    for (int e = t; e < N_EDGES; e += stride) {
        unsigned d = (unsigned)ei[N_EDGES + e];
        d = d < N_NODES ? d : (N_NODES - 1);
        atomicAdd(&deg[d], 1);
    }
}

// -----------------------------------------------------------------------------
// scan (3 kernels, small)
// -----------------------------------------------------------------------------
extern "C" __global__ __launch_bounds__(256)
void scan_bsum_kernel(const int* __restrict__ deg, int* __restrict__ bsum)
{
    __shared__ int sw[4];
    int tid = threadIdx.x;
    int base = blockIdx.x * SCAN_CHUNK + tid * 4;
    int s = 0;
    #pragma unroll
    for (int j = 0; j < 4; ++j) {
        int idx = base + j;
        if (idx < N_NODES) s += deg[idx];
    }
    #pragma unroll
    for (int m = 1; m < 64; m <<= 1) s += __shfl_xor(s, m, 64);
    if ((tid & 63) == 0) sw[tid >> 6] = s;
    __syncthreads();
    if (tid == 0) bsum[blockIdx.x] = sw[0] + sw[1] + sw[2] + sw[3];
}

extern "C" __global__ __launch_bounds__(128)
void scan_top_kernel(int* __restrict__ bsum)
{
    __shared__ int s[128];
    int tid = threadIdx.x;
    int v = (tid < NB_SCAN) ? bsum[tid] : 0;
    s[tid] = v;
    __syncthreads();
    #pragma unroll
    for (int off = 1; off < 128; off <<= 1) {
        int t = (tid >= off) ? s[tid - off] : 0;
        __syncthreads();
        s[tid] += t;
        __syncthreads();
    }
    if (tid < NB_SCAN) bsum[tid] = s[tid] - v;
}

extern "C" __global__ __launch_bounds__(256)
void scan_final_kernel(const int* __restrict__ deg, const int* __restrict__ bsum,
                       int* __restrict__ offs, int* __restrict__ cur)
{
    __shared__ int s[256];
    int tid = threadIdx.x;
    int base = blockIdx.x * SCAN_CHUNK + tid * 4;
    int d[4];
    #pragma unroll
    for (int j = 0; j < 4; ++j) {
        int idx = base + j;
        d[j] = (idx < N_NODES) ? deg[idx] : 0;
    }
    int tot = d[0] + d[1] + d[2] + d[3];
    s[tid] = tot;
    __syncthreads();
    #pragma unroll
    for (int off = 1; off < 256; off <<= 1) {
        int t = (tid >= off) ? s[tid - off] : 0;
        __syncthreads();
        s[tid] += t;
        __syncthreads();
    }
    int b = bsum[blockIdx.x] + s[tid] - tot;
    #pragma unroll
    for (int j = 0; j < 4; ++j) {
        int idx = base + j;
        if (idx < N_NODES) { offs[idx] = b; cur[idx] = b; }
        b += d[j];
    }
}

// -----------------------------------------------------------------------------
// scatter: csr[pos] = edge id, ssrc[pos] = src  (removes ei indirection later)
// -----------------------------------------------------------------------------
extern "C" __global__ __launch_bounds__(256)
void scatter_kernel(const int* __restrict__ ei, int* __restrict__ cur,
                    int* __restrict__ csr, int* __restrict__ ssrc)
{
    int e = blockIdx.x * 256 + threadIdx.x;
    if (e < N_EDGES) {
        unsigned d = (unsigned)ei[N_EDGES + e];
        unsigned s = (unsigned)ei[e];
        d = d < N_NODES ? d : (N_NODES - 1);
        s = s < N_NODES ? s : (N_NODES - 1);
        int pos = atomicAdd(&cur[d], 1);
        csr[pos] = e;
        ssrc[pos] = (int)s;
    }
}

// -----------------------------------------------------------------------------
// fused node kernel: bf16 x-gather aggregation (8-wide masked groups) + 2-layer
// MLP + BN partials. 64-node tile, 8 waves, 8 nodes/wave, lane = feature.
// -----------------------------------------------------------------------------
extern "C" __global__ __launch_bounds__(512)
void node_csr_kernel(const unsigned short* __restrict__ xh,
                     const float* __restrict__ ea,
                     const float* __restrict__ We,
                     const float* __restrict__ be,
                     const int* __restrict__ offs,
                     const int* __restrict__ cur,
                     const int* __restrict__ csr,
                     const int* __restrict__ ssrc,
                     const float* __restrict__ W1,
                     const float* __restrict__ b1,
                     const float* __restrict__ W2,
                     const float* __restrict__ b2,
                     float* __restrict__ out,
                     float* __restrict__ sums)
{
    __shared__ __align__(16) float sW1[DIM * DIM];
    __shared__ __align__(16) float sW2[DIM * DIM];
    __shared__ __align__(16) float sT[DIM * 68];

    int tid  = threadIdx.x;
    int lane = tid & 63;
    int wv   = tid >> 6;
    int base = blockIdx.x * 64;

    for (int i = tid; i < DIM * DIM; i += 512) {
        sW1[i] = W1[i];
        sW2[i] = W2[i];
    }

    float wcol[EDGE_DIM];
    #pragma unroll
    for (int k = 0; k < EDGE_DIM; ++k) wcol[k] = We[k * DIM + lane];
    float bias = be[lane];

    // ---- phase A ----
    #pragma unroll 1
    for (int t = 0; t < 8; ++t) {
        int nl = wv * 8 + t;
        int v  = base + nl;
        float acc = 0.0f;
        if (v < N_NODES) {
            acc = bf2f(xh[(size_t)v * DIM + lane]);
            int stt = __builtin_amdgcn_readfirstlane(offs[v]);
            int end = __builtin_amdgcn_readfirstlane(cur[v]);
            int ng  = (end - stt + 7) >> 3;
            #pragma unroll 1
            for (int g = 0; g < ng; ++g) {
                int i0e = stt + g * 8;
                int e_[8], s_[8];
                #pragma unroll
                for (int u = 0; u < 8; ++u) {
                    int p = i0e + u;
                    p = p < end ? p : end - 1;           // clamp (dup load ok)
                    e_[u] = __builtin_amdgcn_readfirstlane(csr[p]);
                    s_[u] = __builtin_amdgcn_readfirstlane(ssrc[p]);
                }
                float xv[8];
                #pragma unroll
                for (int u = 0; u < 8; ++u)
                    xv[u] = bf2f(xh[(size_t)s_[u] * DIM + lane]);
                float c[8];
                #pragma unroll
                for (int u = 0; u < 8; ++u) {
                    float m = bias;
                    #pragma unroll
                    for (int k = 0; k < EDGE_DIM; ++k)
                        m = fmaf(ea[(size_t)e_[u] * EDGE_DIM + k], wcol[k], m);
                    c[u] = fmaxf(m + xv[u], 0.0f);
                }
                #pragma unroll
                for (int u = 0; u < 8; ++u)
                    acc += (i0e + u < end) ? c[u] : 0.0f;  // uniform predicate
            }
        }
        sT[lane * 68 + nl] = acc;
    }
    __syncthreads();

    // ---- phase B: two GEMMs, 4 nodes x 2 feats per thread ----
    int i0 = (tid & 15) * 4;
    int j0 = (tid >> 4) * 2;

    float acc1[4][2] = {};
    #pragma unroll 8
    for (int k = 0; k < DIM; ++k) {
        float4 av = *(const float4*)&sT[k * 68 + i0];
        float bw0 = sW1[k * DIM + j0];
        float bw1 = sW1[k * DIM + j0 + 1];
        float a4[4] = {av.x, av.y, av.z, av.w};
        #pragma unroll
        for (int a = 0; a < 4; ++a) {
            acc1[a][0] = fmaf(a4[a], bw0, acc1[a][0]);
            acc1[a][1] = fmaf(a4[a], bw1, acc1[a][1]);
        }
    }
    __syncthreads();

    float b1a[2] = {b1[j0], b1[j0 + 1]};
    float tv[4][2];
    #pragma unroll
    for (int a = 0; a < 4; ++a)
        #pragma unroll
        for (int b = 0; b < 2; ++b)
            tv[a][b] = fmaxf(acc1[a][b] + b1a[b], 0.0f);

    #pragma unroll
    for (int b = 0; b < 2; ++b) {
        float4 w = make_float4(tv[0][b], tv[1][b], tv[2][b], tv[3][b]);
        *(float4*)&sT[(j0 + b) * 68 + i0] = w;
    }
    __syncthreads();

    float acc2[4][2] = {};
    #pragma unroll 8
    for (int k = 0; k < DIM; ++k) {
        float4 av = *(const float4*)&sT[k * 68 + i0];
        float bw0 = sW2[k * DIM + j0];
        float bw1 = sW2[k * DIM + j0 + 1];
        float a4[4] = {av.x, av.y, av.z, av.w};
        #pragma unroll
        for (int a = 0; a < 4; ++a) {
            acc2[a][0] = fmaf(a4[a], bw0, acc2[a][0]);
            acc2[a][1] = fmaf(a4[a], bw1, acc2[a][1]);
        }
    }

    float b2a[2] = {b2[j0], b2[j0 + 1]};
    float ps[2] = {0.f, 0.f};
    float pq[2] = {0.f, 0.f};
    #pragma unroll
    for (int a = 0; a < 4; ++a) {
        int n = base + i0 + a;
        float r0 = fmaxf(acc2[a][0] + b2a[0], 0.0f);
        float r1 = fmaxf(acc2[a][1] + b2a[1], 0.0f);
        if (n < N_NODES) {
            float2 w = make_float2(r0, r1);
            *(float2*)&out[(size_t)n * DIM + j0] = w;
            ps[0] += r0; ps[1] += r1;
            pq[0] += r0 * r0; pq[1] += r1 * r1;
        }
    }

    #pragma unroll
    for (int m = 1; m < 16; m <<= 1) {
        #pragma unroll
        for (int b = 0; b < 2; ++b) {
            ps[b] += __shfl_xor(ps[b], m, 64);
            pq[b] += __shfl_xor(pq[b], m, 64);
        }
    }
    if ((lane & 15) == 0) {
        #pragma unroll
        for (int b = 0; b < 2; ++b) {
            unsafeAtomicAdd(&sums[j0 + b], ps[b]);
            unsafeAtomicAdd(&sums[64 + j0 + b], pq[b]);
        }
    }
}

// -----------------------------------------------------------------------------
// BN stats + apply
// -----------------------------------------------------------------------------
extern "C" __global__ void bn_stats_kernel(float* __restrict__ sums,
                                           const float* __restrict__ gamma,
                                           const float* __restrict__ beta)
{
    int f = threadIdx.x;
    float inv_n = 1.0f / (float)N_NODES;
    float mean = sums[f] * inv_n;
    float var  = sums[64 + f] * inv_n - mean * mean;
    float sc   = gamma[f] * rsqrtf(var + BN_EPS);
    sums[128 + f] = sc;
    sums[192 + f] = beta[f] - mean * sc;
}

extern "C" __global__ __launch_bounds__(256)
void bn_apply_kernel(float* __restrict__ out, const float* __restrict__ sums)
{
    int j = blockIdx.x * 256 + threadIdx.x;
    int f0 = (j & 15) * 4;
    float4 sc = *(const float4*)&sums[128 + f0];
    float4 sh = *(const float4*)&sums[192 + f0];
    float4 v = ((float4*)out)[j];
    v.x = fmaf(v.x, sc.x, sh.x);
    v.y = fmaf(v.y, sc.y, sh.y);
    v.z = fmaf(v.z, sc.z, sh.z);
    v.w = fmaf(v.w, sc.w, sh.w);
    ((float4*)out)[j] = v;
}

extern "C" void kernel_launch(void* const* d_in, const int* in_sizes, int n_in,
                              void* d_out, int out_size, void* d_ws, size_t ws_size,
                              hipStream_t stream)
{
    const float* x     = (const float*)d_in[0];
    const int*   ei    = (const int*)  d_in[1];
    const float* ea    = (const float*)d_in[2];
    const float* We    = (const float*)d_in[3];
    const float* be    = (const float*)d_in[4];
    const float* W1    = (const float*)d_in[5];
    const float* b1    = (const float*)d_in[6];
    const float* W2    = (const float*)d_in[7];
    const float* b2    = (const float*)d_in[8];
    const float* gamma = (const float*)d_in[9];
    const float* beta  = (const float*)d_in[10];

    float* out  = (float*)d_out;
    int*   wsi  = (int*)d_ws;
    int*   deg  = wsi + DEG_OFF;
    float* sums = (float*)(wsi + SUMS_OFF_I);
    int*   offs = wsi + OFFS_OFF;
    int*   cur  = wsi + CUR_OFF;
    int*   bsum = wsi + BSUM_OFF;
    int*   csr  = wsi + CSR_OFF;
    int*   ssrc = wsi + SSRC_OFF;
    unsigned short* xh = (unsigned short*)(wsi + XH_OFF_I);

    // zero deg + BN sums in one contiguous memset
    hipMemsetAsync(wsi, 0, (size_t)(N_NODES + 256) * sizeof(int), stream);

    prep_kernel<<<2048, 256, 0, stream>>>(x, xh, ei, deg);
    scan_bsum_kernel<<<NB_SCAN, 256, 0, stream>>>(deg, bsum);
    scan_top_kernel<<<1, 128, 0, stream>>>(bsum);
    scan_final_kernel<<<NB_SCAN, 256, 0, stream>>>(deg, bsum, offs, cur);
    scatter_kernel<<<(N_EDGES + 255) / 256, 256, 0, stream>>>(ei, cur, csr, ssrc);

    node_csr_kernel<<<(N_NODES + 63) / 64, 512, 0, stream>>>(
        xh, ea, We, be, offs, cur, csr, ssrc, W1, b1, W2, b2, out, sums);

    bn_stats_kernel<<<1, 64, 0, stream>>>(sums, gamma, beta);

    bn_apply_kernel<<<(N_NODES * DIM / 4) / 256, 256, 0, stream>>>(out, sums);
}

// Round 5
// 470.923 us; speedup vs baseline: 1.1854x; 1.0390x over previous
//
#include <hip/hip_runtime.h>

#define N_NODES 100000
#define N_EDGES 1250000
#define DIM 64
#define EDGE_DIM 10
#define BN_EPS 1e-5f

#define SCAN_CHUNK 1024
#define NB_SCAN ((N_NODES + SCAN_CHUNK - 1) / SCAN_CHUNK)   // 98

// workspace layout (int units). deg+sums adjacent -> one memset.
#define DEG_OFF    0
#define SUMS_OFF_I (DEG_OFF + N_NODES)        // 256 floats
#define OFFS_OFF   (SUMS_OFF_I + 256)
#define CUR_OFF    (OFFS_OFF + N_NODES)
#define BSUM_OFF   (CUR_OFF + N_NODES)
#define REC_OFF    (BSUM_OFF + 128)
// fast mode: records = 6 ints/edge {src, 5x packed bf16 ea}; slow: 2 ints {src, e}
// xh (bf16 x copy) follows records.

__device__ __forceinline__ float bf2f(unsigned short h) {
    return __uint_as_float(((unsigned)h) << 16);
}
__device__ __forceinline__ unsigned f2bf(float f) {
    unsigned b = __float_as_uint(f);
    return (b + 0x7FFFu + ((b >> 16) & 1u)) >> 16;   // RTNE
}

// -----------------------------------------------------------------------------
// prep: x -> bf16 copy + degree histogram
// -----------------------------------------------------------------------------
extern "C" __global__ __launch_bounds__(256)
void prep_kernel(const float* __restrict__ x, unsigned short* __restrict__ xh,
                 const int* __restrict__ ei, int* __restrict__ deg)
{
    int t = blockIdx.x * 256 + threadIdx.x;
    int stride = gridDim.x * 256;
    for (int i = t; i < N_NODES * DIM; i += stride)
        xh[i] = (unsigned short)f2bf(x[i]);
    for (int e = t; e < N_EDGES; e += stride) {
        unsigned d = (unsigned)ei[N_EDGES + e];
        d = d < N_NODES ? d : (N_NODES - 1);
        atomicAdd(&deg[d], 1);
    }
}

// -----------------------------------------------------------------------------
// scan (3 small kernels)
// -----------------------------------------------------------------------------
extern "C" __global__ __launch_bounds__(256)
void scan_bsum_kernel(const int* __restrict__ deg, int* __restrict__ bsum)
{
    __shared__ int sw[4];
    int tid = threadIdx.x;
    int base = blockIdx.x * SCAN_CHUNK + tid * 4;
    int s = 0;
    #pragma unroll
    for (int j = 0; j < 4; ++j) {
        int idx = base + j;
        if (idx < N_NODES) s += deg[idx];
    }
    #pragma unroll
    for (int m = 1; m < 64; m <<= 1) s += __shfl_xor(s, m, 64);
    if ((tid & 63) == 0) sw[tid >> 6] = s;
    __syncthreads();
    if (tid == 0) bsum[blockIdx.x] = sw[0] + sw[1] + sw[2] + sw[3];
}

extern "C" __global__ __launch_bounds__(128)
void scan_top_kernel(int* __restrict__ bsum)
{
    __shared__ int s[128];
    int tid = threadIdx.x;
    int v = (tid < NB_SCAN) ? bsum[tid] : 0;
    s[tid] = v;
    __syncthreads();
    #pragma unroll
    for (int off = 1; off < 128; off <<= 1) {
        int t = (tid >= off) ? s[tid - off] : 0;
        __syncthreads();
        s[tid] += t;
        __syncthreads();
    }
    if (tid < NB_SCAN) bsum[tid] = s[tid] - v;
}

extern "C" __global__ __launch_bounds__(256)
void scan_final_kernel(const int* __restrict__ deg, const int* __restrict__ bsum,
                       int* __restrict__ offs, int* __restrict__ cur)
{
    __shared__ int s[256];
    int tid = threadIdx.x;
    int base = blockIdx.x * SCAN_CHUNK + tid * 4;
    int d[4];
    #pragma unroll
    for (int j = 0; j < 4; ++j) {
        int idx = base + j;
        d[j] = (idx < N_NODES) ? deg[idx] : 0;
    }
    int tot = d[0] + d[1] + d[2] + d[3];
    s[tid] = tot;
    __syncthreads();
    #pragma unroll
    for (int off = 1; off < 256; off <<= 1) {
        int t = (tid >= off) ? s[tid - off] : 0;
        __syncthreads();
        s[tid] += t;
        __syncthreads();
    }
    int b = bsum[blockIdx.x] + s[tid] - tot;
    #pragma unroll
    for (int j = 0; j < 4; ++j) {
        int idx = base + j;
        if (idx < N_NODES) { offs[idx] = b; cur[idx] = b; }
        b += d[j];
    }
}

// -----------------------------------------------------------------------------
// scatter: one record per edge at its CSR slot.
// fast: {src, ea[10] as 5 packed bf16 dwords} (24 B); slow: {src, e} (8 B)
// -----------------------------------------------------------------------------
extern "C" __global__ __launch_bounds__(256)
void scatter_kernel(const int* __restrict__ ei, const float* __restrict__ ea,
                    int* __restrict__ cur, int* __restrict__ recs, int fast)
{
    int e = blockIdx.x * 256 + threadIdx.x;
    if (e >= N_EDGES) return;
    unsigned d = (unsigned)ei[N_EDGES + e];
    unsigned s = (unsigned)ei[e];
    d = d < N_NODES ? d : (N_NODES - 1);
    s = s < N_NODES ? s : (N_NODES - 1);
    int pos = atomicAdd(&cur[d], 1);
    if (fast) {
        int* r = recs + (size_t)pos * 6;
        r[0] = (int)s;
        #pragma unroll
        for (int k = 0; k < 5; ++k) {
            unsigned lo = f2bf(ea[(size_t)e * EDGE_DIM + 2 * k]);
            unsigned hi = f2bf(ea[(size_t)e * EDGE_DIM + 2 * k + 1]);
            r[1 + k] = (int)(lo | (hi << 16));
        }
    } else {
        int* r = recs + (size_t)pos * 2;
        r[0] = (int)s;
        r[1] = e;
    }
}

// -----------------------------------------------------------------------------
// fused node kernel: record-based aggregation + 2-layer MLP + BN partials.
// 64-node tile, 8 waves, 8 nodes/wave, lane = feature, 8-wide edge groups.
// -----------------------------------------------------------------------------
extern "C" __global__ __launch_bounds__(512)
void node_csr_kernel(const unsigned short* __restrict__ xh,
                     const float* __restrict__ ea,
                     const float* __restrict__ We,
                     const float* __restrict__ be,
                     const int* __restrict__ offs,
                     const int* __restrict__ cur,
                     const int* __restrict__ recs,
                     const float* __restrict__ W1,
                     const float* __restrict__ b1,
                     const float* __restrict__ W2,
                     const float* __restrict__ b2,
                     float* __restrict__ out,
                     float* __restrict__ sums,
                     int fast)
{
    __shared__ __align__(16) float sW1[DIM * DIM];
    __shared__ __align__(16) float sW2[DIM * DIM];
    __shared__ __align__(16) float sT[DIM * 68];

    int tid  = threadIdx.x;
    int lane = tid & 63;
    int wv   = tid >> 6;
    int base = blockIdx.x * 64;

    for (int i = tid; i < DIM * DIM; i += 512) {
        sW1[i] = W1[i];
        sW2[i] = W2[i];
    }

    float wcol[EDGE_DIM];
    #pragma unroll
    for (int k = 0; k < EDGE_DIM; ++k) wcol[k] = We[k * DIM + lane];
    float bias = be[lane];

    // ---- phase A: aggregation ----
    #pragma unroll 1
    for (int t = 0; t < 8; ++t) {
        int nl = wv * 8 + t;
        int v  = base + nl;
        float acc = 0.0f;
        if (v < N_NODES) {
            acc = bf2f(xh[(size_t)v * DIM + lane]);
            int stt = __builtin_amdgcn_readfirstlane(offs[v]);
            int end = __builtin_amdgcn_readfirstlane(cur[v]);
            int ng  = (end - stt + 7) >> 3;
            #pragma unroll 1
            for (int g = 0; g < ng; ++g) {
                int i0e = stt + g * 8;
                int s_[8];
                #pragma unroll
                for (int u = 0; u < 8; ++u) {
                    int p = i0e + u;
                    p = p < end ? p : end - 1;
                    const int* r = recs + (size_t)p * (fast ? 6 : 2);
                    s_[u] = __builtin_amdgcn_readfirstlane(r[0]);
                }
                float xv[8];
                #pragma unroll
                for (int u = 0; u < 8; ++u)
                    xv[u] = bf2f(xh[(size_t)s_[u] * DIM + lane]);
                float c[8];
                #pragma unroll
                for (int u = 0; u < 8; ++u) {
                    int p = i0e + u;
                    p = p < end ? p : end - 1;
                    float m = bias;
                    if (fast) {
                        const int* r = recs + (size_t)p * 6;
                        #pragma unroll
                        for (int k = 0; k < 5; ++k) {
                            unsigned w = (unsigned)__builtin_amdgcn_readfirstlane(r[1 + k]);
                            m = fmaf(__uint_as_float(w << 16),        wcol[2 * k],     m);
                            m = fmaf(__uint_as_float(w & 0xFFFF0000u), wcol[2 * k + 1], m);
                        }
                    } else {
                        int e0 = __builtin_amdgcn_readfirstlane(recs[(size_t)p * 2 + 1]);
                        #pragma unroll
                        for (int k = 0; k < EDGE_DIM; ++k)
                            m = fmaf(ea[(size_t)e0 * EDGE_DIM + k], wcol[k], m);
                    }
                    c[u] = fmaxf(m + xv[u], 0.0f);
                }
                #pragma unroll
                for (int u = 0; u < 8; ++u)
                    acc += (i0e + u < end) ? c[u] : 0.0f;
            }
        }
        sT[lane * 68 + nl] = acc;
    }
    __syncthreads();

    // ---- phase B: two GEMMs, 4 nodes x 2 feats per thread ----
    int i0 = (tid & 15) * 4;
    int j0 = (tid >> 4) * 2;

    float acc1[4][2] = {};
    #pragma unroll 8
    for (int k = 0; k < DIM; ++k) {
        float4 av = *(const float4*)&sT[k * 68 + i0];
        float bw0 = sW1[k * DIM + j0];
        float bw1 = sW1[k * DIM + j0 + 1];
        float a4[4] = {av.x, av.y, av.z, av.w};
        #pragma unroll
        for (int a = 0; a < 4; ++a) {
            acc1[a][0] = fmaf(a4[a], bw0, acc1[a][0]);
            acc1[a][1] = fmaf(a4[a], bw1, acc1[a][1]);
        }
    }
    __syncthreads();

    float b1a[2] = {b1[j0], b1[j0 + 1]};
    float tv[4][2];
    #pragma unroll
    for (int a = 0; a < 4; ++a)
        #pragma unroll
        for (int b = 0; b < 2; ++b)
            tv[a][b] = fmaxf(acc1[a][b] + b1a[b], 0.0f);

    #pragma unroll
    for (int b = 0; b < 2; ++b) {
        float4 w = make_float4(tv[0][b], tv[1][b], tv[2][b], tv[3][b]);
        *(float4*)&sT[(j0 + b) * 68 + i0] = w;
    }
    __syncthreads();

    float acc2[4][2] = {};
    #pragma unroll 8
    for (int k = 0; k < DIM; ++k) {
        float4 av = *(const float4*)&sT[k * 68 + i0];
        float bw0 = sW2[k * DIM + j0];
        float bw1 = sW2[k * DIM + j0 + 1];
        float a4[4] = {av.x, av.y, av.z, av.w};
        #pragma unroll
        for (int a = 0; a < 4; ++a) {
            acc2[a][0] = fmaf(a4[a], bw0, acc2[a][0]);
            acc2[a][1] = fmaf(a4[a], bw1, acc2[a][1]);
        }
    }

    float b2a[2] = {b2[j0], b2[j0 + 1]};
    float ps[2] = {0.f, 0.f};
    float pq[2] = {0.f, 0.f};
    #pragma unroll
    for (int a = 0; a < 4; ++a) {
        int n = base + i0 + a;
        float r0 = fmaxf(acc2[a][0] + b2a[0], 0.0f);
        float r1 = fmaxf(acc2[a][1] + b2a[1], 0.0f);
        if (n < N_NODES) {
            float2 w = make_float2(r0, r1);
            *(float2*)&out[(size_t)n * DIM + j0] = w;
            ps[0] += r0; ps[1] += r1;
            pq[0] += r0 * r0; pq[1] += r1 * r1;
        }
    }

    #pragma unroll
    for (int m = 1; m < 16; m <<= 1) {
        #pragma unroll
        for (int b = 0; b < 2; ++b) {
            ps[b] += __shfl_xor(ps[b], m, 64);
            pq[b] += __shfl_xor(pq[b], m, 64);
        }
    }
    if ((lane & 15) == 0) {
        #pragma unroll
        for (int b = 0; b < 2; ++b) {
            unsafeAtomicAdd(&sums[j0 + b], ps[b]);
            unsafeAtomicAdd(&sums[64 + j0 + b], pq[b]);
        }
    }
}

// -----------------------------------------------------------------------------
// BN stats + apply
// -----------------------------------------------------------------------------
extern "C" __global__ void bn_stats_kernel(float* __restrict__ sums,
                                           const float* __restrict__ gamma,
                                           const float* __restrict__ beta)
{
    int f = threadIdx.x;
    float inv_n = 1.0f / (float)N_NODES;
    float mean = sums[f] * inv_n;
    float var  = sums[64 + f] * inv_n - mean * mean;
    float sc   = gamma[f] * rsqrtf(var + BN_EPS);
    sums[128 + f] = sc;
    sums[192 + f] = beta[f] - mean * sc;
}

extern "C" __global__ __launch_bounds__(256)
void bn_apply_kernel(float* __restrict__ out, const float* __restrict__ sums)
{
    int j = blockIdx.x * 256 + threadIdx.x;
    int f0 = (j & 15) * 4;
    float4 sc = *(const float4*)&sums[128 + f0];
    float4 sh = *(const float4*)&sums[192 + f0];
    float4 v = ((float4*)out)[j];
    v.x = fmaf(v.x, sc.x, sh.x);
    v.y = fmaf(v.y, sc.y, sh.y);
    v.z = fmaf(v.z, sc.z, sh.z);
    v.w = fmaf(v.w, sc.w, sh.w);
    ((float4*)out)[j] = v;
}

extern "C" void kernel_launch(void* const* d_in, const int* in_sizes, int n_in,
                              void* d_out, int out_size, void* d_ws, size_t ws_size,
                              hipStream_t stream)
{
    const float* x     = (const float*)d_in[0];
    const int*   ei    = (const int*)  d_in[1];
    const float* ea    = (const float*)d_in[2];
    const float* We    = (const float*)d_in[3];
    const float* be    = (const float*)d_in[4];
    const float* W1    = (const float*)d_in[5];
    const float* b1    = (const float*)d_in[6];
    const float* W2    = (const float*)d_in[7];
    const float* b2    = (const float*)d_in[8];
    const float* gamma = (const float*)d_in[9];
    const float* beta  = (const float*)d_in[10];

    float* out  = (float*)d_out;
    int*   wsi  = (int*)d_ws;
    int*   deg  = wsi + DEG_OFF;
    float* sums = (float*)(wsi + SUMS_OFF_I);
    int*   offs = wsi + OFFS_OFF;
    int*   cur  = wsi + CUR_OFF;
    int*   bsum = wsi + BSUM_OFF;
    int*   recs = wsi + REC_OFF;

    // fast mode needs 24 B/edge records + xh: check workspace
    size_t need_fast = ((size_t)REC_OFF + 6u * N_EDGES + (size_t)N_NODES * DIM / 2) * 4u;
    int fast = (ws_size >= need_fast) ? 1 : 0;
    int rec_ints = fast ? 6 * N_EDGES : 2 * N_EDGES;
    unsigned short* xh = (unsigned short*)(wsi + REC_OFF + rec_ints);

    // zero deg + BN sums (adjacent) in one memset
    hipMemsetAsync(wsi, 0, (size_t)(N_NODES + 256) * sizeof(int), stream);

    prep_kernel<<<2048, 256, 0, stream>>>(x, xh, ei, deg);
    scan_bsum_kernel<<<NB_SCAN, 256, 0, stream>>>(deg, bsum);
    scan_top_kernel<<<1, 128, 0, stream>>>(bsum);
    scan_final_kernel<<<NB_SCAN, 256, 0, stream>>>(deg, bsum, offs, cur);
    scatter_kernel<<<(N_EDGES + 255) / 256, 256, 0, stream>>>(ei, ea, cur, recs, fast);

    node_csr_kernel<<<(N_NODES + 63) / 64, 512, 0, stream>>>(
        xh, ea, We, be, offs, cur, recs, W1, b1, W2, b2, out, sums, fast);

    bn_stats_kernel<<<1, 64, 0, stream>>>(sums, gamma, beta);

    bn_apply_kernel<<<(N_NODES * DIM / 4) / 256, 256, 0, stream>>>(out, sums);
}